// Round 5
// baseline (1060.975 us; speedup 1.0000x reference)
//
#include <hip/hip_runtime.h>
#include <cstdint>
#include <cstddef>

// BooleanReservoir — persistent cooperative kernel, v4.
// lane = batch; states[node] = u64 (bit b = batch b). Packed LUT + adjacency in
// LDS for all 128 steps; cross-block state traffic via device-scope relaxed
// atomics (L3-coherent, no cache-maintenance ops).
// R5 changes: (1) last-arriver-releases 2-level barrier (64 leaves -> root ->
// 8 go-flags), no leader poll level; (2) 256 blocks x 1024 threads (1/CU);
// (3) gathers redirect node-id<64 to precomputed u_all[t] (u-writer wave gone);
// (4) one multi-lane state store per wave.

#define N_NODES   20000
#define N_INPUT   64
#define K_MAX     12
#define T_STEPS   128
#define N_BATCH   64
#define N_OUT     10
#define N_FEAT    (N_NODES - N_INPUT)   // 19936
#define DUMMY_NODE 20000                // always-zero state word
#define ST_WORDS  20004

#define NBLK 256
#define NTHR 1024                       // 16 waves/block, 1 block/CU
#define NPB  78                         // nodes/block: 256*78 = 19968 >= 19936
#define NPB_PAD 80                      // 16 waves * 5 nodes
#define LEAF_CNT 64                     // arrival leaves (4 arrivals each)
#define GO_CNT  8                       // go-flags (release fan-out)
#define BAR_STRIDE 32                   // u32 units -> 128 B apart
#define ROOT_IDX 64                     // bar slot layout: [0..63] leaf, 64 root, 65..72 go

typedef unsigned long long u64;

// ---------------- pack x: xp[t][b] = bits j of x[b][t][j] ----------------
__global__ __launch_bounds__(256) void pack_x_kernel(const int* __restrict__ x,
                                                     u64* __restrict__ xp) {
  const int t = blockIdx.x;
  const int wave = threadIdx.x >> 6, lane = threadIdx.x & 63;
  for (int b = wave; b < N_BATCH; b += 4) {
    int v = x[((size_t)b * T_STEPS + t) * 64 + lane];
    u64 bal = __ballot(v != 0);
    if (lane == 0) xp[(size_t)t * N_BATCH + b] = bal;
  }
}

// -------- init state buffers, wcol, barrier slots --------
__global__ __launch_bounds__(256) void init_kernel(const int* __restrict__ inis,
                                                   const int* __restrict__ w_in,
                                                   u64* __restrict__ buf0,
                                                   u64* __restrict__ buf1,
                                                   u64* __restrict__ wcol,
                                                   unsigned* __restrict__ bar) {
  if (blockIdx.x < 79) {
    int n = blockIdx.x * 256 + threadIdx.x;
    if (n >= N_INPUT && n < ST_WORDS) {
      u64 w = (n < N_NODES && inis[n] != 0) ? ~0ull : 0ull;   // dummy/pad -> 0
      buf0[n] = w;
      buf1[n] = w;   // no-neigh nodes never rewritten: init lives in both buffers
    }
  } else {
    const int wave = threadIdx.x >> 6, lane = threadIdx.x & 63;
    for (int i = wave; i < 64; i += 4) {
      int wv = w_in[(size_t)lane * 64 + i];  // lane = j
      u64 wc = __ballot(wv != 0);
      if (lane == 0) wcol[i] = wc;
    }
    if (threadIdx.x < ROOT_IDX + 1 + GO_CNT) // ws re-poisoned each call
      bar[threadIdx.x * BAR_STRIDE] = 0u;
  }
}

// -------- precompute u(t) for all t: u_all[t*64+i] bit b = (xp[t][b]&wcol[i])!=0 --------
__global__ __launch_bounds__(64) void u_pre_kernel(const u64* __restrict__ xp,
                                                   const u64* __restrict__ wcol,
                                                   u64* __restrict__ u_all) {
  const int t = blockIdx.x, lane = threadIdx.x;
  u64 xw = xp[(size_t)t * N_BATCH + lane];   // lane = batch
  for (int i = 0; i < 64; i++) {
    u64 ub = __ballot((xw & wcol[i]) != 0);
    if (lane == 0) u_all[(size_t)t * 64 + i] = ub;
  }
}

// ---- 64x64 bit transpose: lane l holds row l; returns lane b holding column b ----
__device__ __forceinline__ u64 bit_transpose64(u64 w, int lane) {
  const u64 LO0 = 0x00000000FFFFFFFFull, LO1 = 0x0000FFFF0000FFFFull,
            LO2 = 0x00FF00FF00FF00FFull, LO3 = 0x0F0F0F0F0F0F0F0Full,
            LO4 = 0x3333333333333333ull, LO5 = 0x5555555555555555ull;
#define XP_STAGE(d, LO)                                                  \
  {                                                                      \
    u64 p = (u64)__shfl_xor((long long)w, (d), 64);                      \
    if (lane & (d)) w = ((p >> (d)) & (LO)) | (w & ~(LO));               \
    else            w = (w & (LO)) | ((p << (d)) & ~(LO));               \
  }
  XP_STAGE(32, LO0) XP_STAGE(16, LO1) XP_STAGE(8, LO2)
  XP_STAGE(4,  LO3) XP_STAGE(2,  LO4) XP_STAGE(1, LO5)
#undef XP_STAGE
  return w;
}

// ---------------- persistent reservoir: all 128 steps ----------------
__global__ __launch_bounds__(NTHR) void reservoir_kernel(
    const int* __restrict__ lut, const int* __restrict__ adj,
    const int* __restrict__ mask, const u64* __restrict__ u_all,
    u64* __restrict__ buf0, u64* __restrict__ buf1,
    unsigned* __restrict__ bar) {
  __shared__ u64 lut_lds[NPB_PAD * 64];        // 40960 B
  __shared__ int adj_lds[NPB_PAD * K_MAX];     //  3840 B
  __shared__ unsigned char hn_lds[NPB_PAD];

  const int bi = blockIdx.x;
  const int tid = threadIdx.x;
  const int wave = tid >> 6, lane = tid & 63;
  const int base = N_INPUT + bi * NPB;
  const int nloc = min(NPB, N_NODES - base);   // last block: 46

  // ---- prologue: adjacency (slot-REVERSED: slot j at offset 11-j) + hn ----
  // After transpose, lane b's bit (12i + (11-j)) = neighbor j -> the field
  // (w >> 12i) & 0xFFF is directly the reference's MSB-first LUT index.
  if (tid < NPB_PAD) {
    int i = tid, h = 0;
    if (i < nloc) {
      for (int j = 0; j < K_MAX; j++) {
        int m = mask[(size_t)(base + i) * K_MAX + j];
        int a = adj[(size_t)(base + i) * K_MAX + j];
        adj_lds[i * K_MAX + (K_MAX - 1 - j)] = m ? a : DUMMY_NODE;
        h |= m;
      }
    } else {
      for (int j = 0; j < K_MAX; j++) adj_lds[i * K_MAX + j] = DUMMY_NODE;
    }
    hn_lds[i] = (unsigned char)(h ? 1 : 0);
  }

  // ---- prologue: pack this block's LUT slice into LDS ----
  const int nwords = nloc * 64;
  const int* lp = lut + (size_t)base * 4096;
  for (int w0 = wave * 8; w0 < nwords; w0 += 128) {   // 16 waves x 8 words
    int v[8];
#pragma unroll
    for (int q = 0; q < 8; q++) {
      int widx = w0 + q;
      v[q] = (widx < nwords) ? lp[(size_t)widx * 64 + lane] : 0;   // coalesced 256B
    }
#pragma unroll
    for (int q = 0; q < 8; q++) {
      int widx = w0 + q;
      u64 bal = __ballot(v[q] != 0);
      if (lane == 0 && widx < nwords) lut_lds[widx] = bal;
    }
  }
  __syncthreads();   // block-local; step 0 reads init_kernel's buf0 (launch-ordered)

  const int l0 = wave * 5;                     // this wave's first local node
  const int cnt = min(5, nloc - l0);           // may be <= 0
  const bool do_store = (lane < cnt) && hn_lds[l0 + lane];  // lane i -> node l0+i

  // ---- 128 steps ----
  for (int t = 0; t < T_STEPS; t++) {
    u64* cur = (t & 1) ? buf1 : buf0;
    u64* nxt = (t & 1) ? buf0 : buf1;
    const u64* ubase = u_all + (size_t)t * 64;

    // gather: lane l (<60) -> neighbor word for (node l/12, rev-slot l%12);
    // node-ids < 64 redirect to the precomputed input words u_all[t]
    u64 w = 0;
    if (lane < 60) {
      int a = adj_lds[l0 * K_MAX + lane];      // pad slots hold DUMMY
      const u64* p = (a < N_INPUT) ? (ubase + a) : (cur + a);
      w = __hip_atomic_load(p, __ATOMIC_RELAXED, __HIP_MEMORY_SCOPE_AGENT);
    }
    // transpose: lane b now holds all 60 index bits for batch b
    w = bit_transpose64(w, lane);

    u64 keep = 0;
#pragma unroll
    for (int i = 0; i < 5; i++) {
      if (i < cnt) {                           // wave-uniform
        unsigned idx = (unsigned)(w >> (12 * i)) & 0xFFFu;   // MSB-first index
        u64 g = lut_lds[(l0 + i) * 64 + (idx >> 6)];
        u64 res = __ballot((g >> (idx & 63)) & 1ull);
        if (lane == i) keep = res;
      }
    }
    if (do_store)                               // one vmem store, lanes 0..cnt-1
      __hip_atomic_store(&nxt[base + l0 + lane], keep,
                         __ATOMIC_RELAXED, __HIP_MEMORY_SCOPE_AGENT);

    // ---- last-arriver-releases grid barrier (no cache-maintenance ops) ----
    if (t != T_STEPS - 1) {
      __syncthreads();   // all waves drain vmcnt: stores visible at L3
      __builtin_amdgcn_fence(__ATOMIC_RELEASE, "workgroup");  // compiler ordering
      if (wave == 0) {
        unsigned leafold = 0;
        if (lane == 0)
          leafold = __hip_atomic_fetch_add(&bar[(bi & (LEAF_CNT - 1)) * BAR_STRIDE],
                                           1u, __ATOMIC_RELAXED, __HIP_MEMORY_SCOPE_AGENT);
        leafold = (unsigned)__shfl((int)leafold, 0);
        if (leafold == (unsigned)t * (NBLK / LEAF_CNT) + (NBLK / LEAF_CNT - 1)) {
          unsigned rootold = 0;
          if (lane == 0)
            rootold = __hip_atomic_fetch_add(&bar[ROOT_IDX * BAR_STRIDE], 1u,
                                             __ATOMIC_RELAXED, __HIP_MEMORY_SCOPE_AGENT);
          rootold = (unsigned)__shfl((int)rootold, 0);
          if (rootold == (unsigned)t * LEAF_CNT + (LEAF_CNT - 1) && lane < GO_CNT)
            __hip_atomic_store(&bar[(ROOT_IDX + 1 + lane) * BAR_STRIDE],
                               (unsigned)(t + 1),
                               __ATOMIC_RELAXED, __HIP_MEMORY_SCOPE_AGENT);
        }
        // all 64 lanes poll the SAME go-flag -> one L3 request per round
        unsigned* gp = &bar[(ROOT_IDX + 1 + (bi & (GO_CNT - 1))) * BAR_STRIDE];
        while (__hip_atomic_load(gp, __ATOMIC_RELAXED, __HIP_MEMORY_SCOPE_AGENT)
               < (unsigned)(t + 1))
          __builtin_amdgcn_s_sleep(1);
      }
      __builtin_amdgcn_fence(__ATOMIC_ACQUIRE, "workgroup");  // compiler ordering
      __syncthreads();
    }
  }
}

// ---------------- readout: sigmoid(feats @ W_out^T + b_out) ----------------
__global__ __launch_bounds__(256) void readout_kernel(const u64* __restrict__ st,
                                                      const float* __restrict__ Wout,
                                                      const float* __restrict__ bout,
                                                      float* __restrict__ out) {
  const int b = blockIdx.x / N_OUT;
  const int o = blockIdx.x % N_OUT;
  float acc = 0.f;
  for (int n = threadIdx.x; n < N_FEAT; n += 256) {
    u64 s = st[N_INPUT + n];
    float w = Wout[(size_t)o * N_FEAT + n];
    acc += ((s >> b) & 1ull) ? w : 0.f;
  }
  for (int off = 32; off > 0; off >>= 1) acc += __shfl_down(acc, off);
  __shared__ float red[4];
  const int wave = threadIdx.x >> 6, lane = threadIdx.x & 63;
  if (lane == 0) red[wave] = acc;
  __syncthreads();
  if (threadIdx.x == 0) {
    float tot = red[0] + red[1] + red[2] + red[3] + bout[o];
    out[(size_t)b * N_OUT + o] = 1.f / (1.f + __expf(-tot));
  }
}

extern "C" void kernel_launch(void* const* d_in, const int* in_sizes, int n_in,
                              void* d_out, int out_size, void* d_ws, size_t ws_size,
                              hipStream_t stream) {
  const int* x    = (const int*)d_in[0];
  const int* w_in = (const int*)d_in[1];
  const int* adj  = (const int*)d_in[2];
  const int* mask = (const int*)d_in[3];
  const int* lut  = (const int*)d_in[4];
  const int* inis = (const int*)d_in[5];
  const float* Wout = (const float*)d_in[6];
  const float* bout = (const float*)d_in[7];
  float* out = (float*)d_out;

  char* ws = (char*)d_ws;
  size_t off = 0;
  auto alloc = [&](size_t bytes) -> void* {
    void* p = ws + off;
    off += (bytes + 255) & ~(size_t)255;
    return p;
  };
  u64* buf0 = (u64*)alloc((size_t)ST_WORDS * 8);
  u64* buf1 = (u64*)alloc((size_t)ST_WORDS * 8);
  u64* xp   = (u64*)alloc((size_t)T_STEPS * N_BATCH * 8);
  u64* wcol = (u64*)alloc(64 * 8);
  u64* u_all = (u64*)alloc((size_t)T_STEPS * 64 * 8);         // 64 KB
  unsigned* bar = (unsigned*)alloc((size_t)(ROOT_IDX + 1 + GO_CNT) * BAR_STRIDE * 4);
  (void)ws_size; (void)in_sizes; (void)n_in; (void)out_size;

  hipLaunchKernelGGL(pack_x_kernel, dim3(T_STEPS), dim3(256), 0, stream, x, xp);
  hipLaunchKernelGGL(init_kernel, dim3(80), dim3(256), 0, stream,
                     inis, w_in, buf0, buf1, wcol, bar);
  hipLaunchKernelGGL(u_pre_kernel, dim3(T_STEPS), dim3(64), 0, stream,
                     xp, wcol, u_all);

  void* args[] = {(void*)&lut, (void*)&adj, (void*)&mask, (void*)&u_all,
                  (void*)&buf0, (void*)&buf1, (void*)&bar};
  hipLaunchCooperativeKernel((const void*)reservoir_kernel,
                             dim3(NBLK), dim3(NTHR), args, 0, stream);

  // T even -> final states in buf0
  hipLaunchKernelGGL(readout_kernel, dim3(N_BATCH * N_OUT), dim3(256), 0, stream,
                     buf0, Wout, bout, out);
}